// Round 1
// baseline (169.388 us; speedup 1.0000x reference)
//
#include <hip/hip_runtime.h>
#include <math.h>

#define N_G   512
#define IMG_H 256
#define IMG_W 256
#define REC   16   // floats per sorted gaussian record

// record layout: [0]=mx [1]=my [2]=i00 [3]=i01 [4]=i11 [5]=op
//                [6]=r [7]=g [8]=b [9]=dep [10]=xlo [11]=xhi
//                [12]=ylo [13]=yhi [14]=vis [15]=pad

__global__ __launch_bounds__(N_G) void preprocess_sort(
    const float* __restrict__ xyz, const float* __restrict__ opacity,
    const float* __restrict__ features, const float* __restrict__ cov,
    const float* __restrict__ Km, const float* __restrict__ w2c,
    float* __restrict__ radii_out, float* __restrict__ sorted_recs)
{
    __shared__ float skey[N_G];
    const int n = threadIdx.x;

    // camera
    const float R00=w2c[0], R01=w2c[1], R02=w2c[2],  t0=w2c[3];
    const float R10=w2c[4], R11=w2c[5], R12=w2c[6],  t1=w2c[7];
    const float R20=w2c[8], R21=w2c[9], R22=w2c[10], t2=w2c[11];
    const float K00=Km[0],K01=Km[1],K02=Km[2];
    const float K10=Km[3],K11=Km[4],K12=Km[5];
    const float K20=Km[6],K21=Km[7],K22=Km[8];

    const float wx = xyz[n*3+0], wy = xyz[n*3+1], wz = xyz[n*3+2];
    const float cx = R00*wx + R01*wy + R02*wz + t0;
    const float cy = R10*wx + R11*wy + R12*wz + t1;
    const float cz = R20*wx + R21*wy + R22*wz + t2;
    const float depth = cz;

    const float xh = K00*cx + K01*cy + K02*cz;
    const float yh = K10*cx + K11*cy + K12*cz;
    const float zh = K20*cx + K21*cy + K22*cz;
    const float zc = fmaxf(zh, 1e-8f);
    const float mx = xh / zc, my = yh / zc;

    // cam_pos = inv(w2c)[:3,3]  (rigid inverse: -R^T t; exact for the identity w2c)
    const float cpx = -(R00*t0 + R10*t1 + R20*t2);
    const float cpy = -(R01*t0 + R11*t1 + R21*t2);
    const float cpz = -(R02*t0 + R12*t1 + R22*t2);
    float vx = wx - cpx, vy = wy - cpy, vz = wz - cpz;
    const float nrm = fmaxf(sqrtf(vx*vx + vy*vy + vz*vz), 1e-12f);
    vx /= nrm; vy /= nrm; vz /= nrm;

    // SH basis (degree 3, 16 coeffs)
    const float xx=vx*vx, yy=vy*vy, zz=vz*vz;
    const float sxy=vx*vy, syz=vy*vz, sxz=vx*vz;
    float sb[16];
    sb[0]  = 0.28209479177387814f;
    sb[1]  = -0.4886025119029199f*vy;
    sb[2]  =  0.4886025119029199f*vz;
    sb[3]  = -0.4886025119029199f*vx;
    sb[4]  =  1.0925484305920792f*sxy;
    sb[5]  = -1.0925484305920792f*syz;
    sb[6]  =  0.31539156525252005f*(2.f*zz - xx - yy);
    sb[7]  = -1.0925484305920792f*sxz;
    sb[8]  =  0.5462742152960396f*(xx - yy);
    sb[9]  = -0.5900435899266435f*vy*(3.f*xx - yy);
    sb[10] =  2.890611442640554f*sxy*vz;
    sb[11] = -0.4570457994644658f*vy*(4.f*zz - xx - yy);
    sb[12] =  0.3731763325901154f*vz*(2.f*zz - 3.f*xx - 3.f*yy);
    sb[13] = -0.4570457994644658f*vx*(4.f*zz - xx - yy);
    sb[14] =  1.445305721320277f*vz*(xx - yy);
    sb[15] = -0.5900435899266435f*vx*(xx - 3.f*yy);

    float cr = 0.f, cg = 0.f, cb = 0.f;
    const float* sh = &features[n*48];
    #pragma unroll
    for (int k = 0; k < 16; ++k) {
        cr += sb[k]*sh[k*3+0];
        cg += sb[k]*sh[k*3+1];
        cb += sb[k]*sh[k*3+2];
    }
    cr = fminf(fmaxf(cr + 0.5f, 0.f), 1.f);
    cg = fminf(fmaxf(cg + 0.5f, 0.f), 1.f);
    cb = fminf(fmaxf(cb + 0.5f, 0.f), 1.f);

    // 2D covariance: J rows 0,1; T = J*R; cov2d = T Sigma T^T + 0.3 I
    const float fx = K00, fy = K11;
    const float tz = fmaxf(cz, 1e-8f);
    const float tz2 = tz*tz;
    const float J00 = fx/tz,  J02 = -fx*cx/tz2;
    const float J11 = fy/tz,  J12 = -fy*cy/tz2;
    const float T00 = J00*R00 + J02*R20;
    const float T01 = J00*R01 + J02*R21;
    const float T02 = J00*R02 + J02*R22;
    const float T10 = J11*R10 + J12*R20;
    const float T11 = J11*R11 + J12*R21;
    const float T12 = J11*R12 + J12*R22;
    const float* S = &cov[n*9];
    const float u0 = S[0]*T00 + S[1]*T01 + S[2]*T02;
    const float u1 = S[3]*T00 + S[4]*T01 + S[5]*T02;
    const float u2 = S[6]*T00 + S[7]*T01 + S[8]*T02;
    const float a  = T00*u0 + T01*u1 + T02*u2 + 0.3f;
    const float bb = T10*u0 + T11*u1 + T12*u2;          // Sigma symmetric
    const float w0 = S[0]*T10 + S[1]*T11 + S[2]*T12;
    const float w1 = S[3]*T10 + S[4]*T11 + S[5]*T12;
    const float w2 = S[6]*T10 + S[7]*T11 + S[8]*T12;
    const float d  = T10*w0 + T11*w1 + T12*w2 + 0.3f;

    const float det   = a*d - bb*bb;
    const float trace = a + d;
    const float lam   = 0.5f*(trace + sqrtf(fmaxf(trace*trace - 4.f*det, 0.f)));
    const float radii_f = 3.f*sqrtf(fmaxf(lam, 1e-8f));

    const bool visible = (depth > 0.01f) &&
                         (mx > -256.f) && (mx < (float)IMG_W + 256.f) &&
                         (my > -256.f) && (my < (float)IMG_H + 256.f);
    radii_out[n] = visible ? radii_f : 0.f;

    const float det_c = fmaxf(det, 1e-10f);
    const float i00 =  d / det_c;
    const float i01 = -bb / det_c;
    const float i11 =  a / det_c;

    const float rad = fmaxf(radii_f, 1.f);
    const float xlo = floorf(fminf(fmaxf(mx - rad,      0.f), (float)IMG_W));
    const float xhi = floorf(fminf(fmaxf(mx + rad + 1.f, 0.f), (float)IMG_W));
    const float ylo = floorf(fminf(fmaxf(my - rad,      0.f), (float)IMG_H));
    const float yhi = floorf(fminf(fmaxf(my + rad + 1.f, 0.f), (float)IMG_H));

    // stable rank sort on key = visible ? depth : +inf (matches jnp.argsort)
    const float key = visible ? depth : INFINITY;
    skey[n] = key;
    __syncthreads();
    int rank = 0;
    for (int j = 0; j < N_G; ++j) {
        const float kj = skey[j];
        rank += (kj < key) || (kj == key && j < n);
    }

    float* r = &sorted_recs[rank*REC];
    r[0] = mx;  r[1] = my;  r[2] = i00; r[3] = i01; r[4] = i11;
    r[5] = opacity[n];
    r[6] = cr;  r[7] = cg;  r[8] = cb;  r[9] = depth;
    r[10] = xlo; r[11] = xhi; r[12] = ylo; r[13] = yhi;
    r[14] = visible ? 1.f : 0.f; r[15] = 0.f;
}

__global__ __launch_bounds__(256) void rasterize(
    const float* __restrict__ recs, const float* __restrict__ bg,
    float* __restrict__ out)
{
    __shared__ float s[N_G*REC];
    {
        const float4* src = (const float4*)recs;
        float4* dst = (float4*)s;
        for (int i = threadIdx.x; i < N_G*REC/4; i += 256) dst[i] = src[i];
    }
    __syncthreads();

    const int lx = threadIdx.x & 15, ly = threadIdx.x >> 4;
    const int pxi = blockIdx.x*16 + lx;
    const int pyi = blockIdx.y*16 + ly;
    const float fpx = (float)pxi, fpy = (float)pyi;

    float T = 1.f, cr = 0.f, cg = 0.f, cb = 0.f, D = 0.f;

    for (int g = 0; g < N_G; ++g) {
        const float* r = &s[g*REC];   // wave-uniform g -> LDS broadcast, no conflicts
        if (r[14] != 0.f &&
            fpx >= r[10] && fpx < r[11] && fpy >= r[12] && fpy < r[13]) {
            const float dx = fpx - r[0], dy = fpy - r[1];
            const float maha = r[2]*dx*dx + 2.f*r[3]*dx*dy + r[4]*dy*dy;
            const float alpha = fminf(r[5]*__expf(-0.5f*maha), 0.99f);
            const float w = T*alpha;
            cr += w*r[6]; cg += w*r[7]; cb += w*r[8]; D += w*r[9];
            T *= (1.f - alpha);
        }
        if (__all(T < 1e-7f)) break;   // all 64 lanes saturated
    }

    const int p = pyi*IMG_W + pxi;
    const float b0 = bg[0], b1 = bg[1], b2 = bg[2];
    out[p]                      = cr + b0*T;
    out[IMG_H*IMG_W   + p]      = cg + b1*T;
    out[2*IMG_H*IMG_W + p]      = cb + b2*T;
    out[3*IMG_H*IMG_W + p]      = D;
    out[4*IMG_H*IMG_W + p]      = 1.f - T;
}

extern "C" void kernel_launch(void* const* d_in, const int* in_sizes, int n_in,
                              void* d_out, int out_size, void* d_ws, size_t ws_size,
                              hipStream_t stream) {
    const float* xyz      = (const float*)d_in[0];
    const float* opacity  = (const float*)d_in[1];
    const float* features = (const float*)d_in[2];
    const float* cov      = (const float*)d_in[3];
    const float* Km       = (const float*)d_in[4];
    const float* w2c      = (const float*)d_in[5];
    const float* bg       = (const float*)d_in[6];
    float* out = (float*)d_out;
    float* sorted_recs = (float*)d_ws;           // 512*16*4 = 32 KB
    float* radii_out = out + 5*IMG_H*IMG_W;      // after render(3)+depth(1)+alpha(1) planes

    preprocess_sort<<<1, N_G, 0, stream>>>(xyz, opacity, features, cov, Km, w2c,
                                           radii_out, sorted_recs);
    rasterize<<<dim3(IMG_W/16, IMG_H/16), 256, 0, stream>>>(sorted_recs, bg, out);
}

// Round 2
// 89.145 us; speedup vs baseline: 1.9001x; 1.9001x over previous
//
#include <hip/hip_runtime.h>
#include <math.h>

#define N_G   512
#define IMG_H 256
#define IMG_W 256

// record layout: 4 x float4 per gaussian (64 B)
//  q0 = (xlo, xhi, ylo, yhi)   -- sentinel (1e9,-1e9,1e9,-1e9) if invisible
//  q1 = (mx,  my,  i00, i01)
//  q2 = (i11, op,  dep, 0)
//  q3 = (r,   g,   b,   0)

__global__ __launch_bounds__(N_G) void preprocess_sort(
    const float* __restrict__ xyz, const float* __restrict__ opacity,
    const float* __restrict__ features, const float* __restrict__ cov,
    const float* __restrict__ Km, const float* __restrict__ w2c,
    float* __restrict__ radii_out, float4* __restrict__ recs)
{
    __shared__ float skey[N_G];
    const int n = threadIdx.x;

    const float R00=w2c[0], R01=w2c[1], R02=w2c[2],  t0=w2c[3];
    const float R10=w2c[4], R11=w2c[5], R12=w2c[6],  t1=w2c[7];
    const float R20=w2c[8], R21=w2c[9], R22=w2c[10], t2=w2c[11];
    const float K00=Km[0],K01=Km[1],K02=Km[2];
    const float K10=Km[3],K11=Km[4],K12=Km[5];
    const float K20=Km[6],K21=Km[7],K22=Km[8];

    const float wx = xyz[n*3+0], wy = xyz[n*3+1], wz = xyz[n*3+2];
    const float cx = R00*wx + R01*wy + R02*wz + t0;
    const float cy = R10*wx + R11*wy + R12*wz + t1;
    const float cz = R20*wx + R21*wy + R22*wz + t2;
    const float depth = cz;

    const float xh = K00*cx + K01*cy + K02*cz;
    const float yh = K10*cx + K11*cy + K12*cz;
    const float zh = K20*cx + K21*cy + K22*cz;
    const float zc = fmaxf(zh, 1e-8f);
    const float mx = xh / zc, my = yh / zc;

    // cam_pos = inv(w2c)[:3,3] (rigid inverse; exact for identity w2c)
    const float cpx = -(R00*t0 + R10*t1 + R20*t2);
    const float cpy = -(R01*t0 + R11*t1 + R21*t2);
    const float cpz = -(R02*t0 + R12*t1 + R22*t2);
    float vx = wx - cpx, vy = wy - cpy, vz = wz - cpz;
    const float nrm = fmaxf(sqrtf(vx*vx + vy*vy + vz*vz), 1e-12f);
    vx /= nrm; vy /= nrm; vz /= nrm;

    const float xx=vx*vx, yy=vy*vy, zz=vz*vz;
    const float sxy=vx*vy, syz=vy*vz, sxz=vx*vz;
    float sb[16];
    sb[0]  = 0.28209479177387814f;
    sb[1]  = -0.4886025119029199f*vy;
    sb[2]  =  0.4886025119029199f*vz;
    sb[3]  = -0.4886025119029199f*vx;
    sb[4]  =  1.0925484305920792f*sxy;
    sb[5]  = -1.0925484305920792f*syz;
    sb[6]  =  0.31539156525252005f*(2.f*zz - xx - yy);
    sb[7]  = -1.0925484305920792f*sxz;
    sb[8]  =  0.5462742152960396f*(xx - yy);
    sb[9]  = -0.5900435899266435f*vy*(3.f*xx - yy);
    sb[10] =  2.890611442640554f*sxy*vz;
    sb[11] = -0.4570457994644658f*vy*(4.f*zz - xx - yy);
    sb[12] =  0.3731763325901154f*vz*(2.f*zz - 3.f*xx - 3.f*yy);
    sb[13] = -0.4570457994644658f*vx*(4.f*zz - xx - yy);
    sb[14] =  1.445305721320277f*vz*(xx - yy);
    sb[15] = -0.5900435899266435f*vx*(xx - 3.f*yy);

    float cr = 0.f, cg = 0.f, cb = 0.f;
    const float* sh = &features[n*48];
    #pragma unroll
    for (int k = 0; k < 16; ++k) {
        cr += sb[k]*sh[k*3+0];
        cg += sb[k]*sh[k*3+1];
        cb += sb[k]*sh[k*3+2];
    }
    cr = fminf(fmaxf(cr + 0.5f, 0.f), 1.f);
    cg = fminf(fmaxf(cg + 0.5f, 0.f), 1.f);
    cb = fminf(fmaxf(cb + 0.5f, 0.f), 1.f);

    const float fx = K00, fy = K11;
    const float tz = fmaxf(cz, 1e-8f);
    const float tz2 = tz*tz;
    const float J00 = fx/tz,  J02 = -fx*cx/tz2;
    const float J11 = fy/tz,  J12 = -fy*cy/tz2;
    const float T00 = J00*R00 + J02*R20;
    const float T01 = J00*R01 + J02*R21;
    const float T02 = J00*R02 + J02*R22;
    const float T10 = J11*R10 + J12*R20;
    const float T11 = J11*R11 + J12*R21;
    const float T12 = J11*R12 + J12*R22;
    const float* S = &cov[n*9];
    const float u0 = S[0]*T00 + S[1]*T01 + S[2]*T02;
    const float u1 = S[3]*T00 + S[4]*T01 + S[5]*T02;
    const float u2 = S[6]*T00 + S[7]*T01 + S[8]*T02;
    const float a  = T00*u0 + T01*u1 + T02*u2 + 0.3f;
    const float bb = T10*u0 + T11*u1 + T12*u2;
    const float w0 = S[0]*T10 + S[1]*T11 + S[2]*T12;
    const float w1 = S[3]*T10 + S[4]*T11 + S[5]*T12;
    const float w2 = S[6]*T10 + S[7]*T11 + S[8]*T12;
    const float d  = T10*w0 + T11*w1 + T12*w2 + 0.3f;

    const float det   = a*d - bb*bb;
    const float trace = a + d;
    const float lam   = 0.5f*(trace + sqrtf(fmaxf(trace*trace - 4.f*det, 0.f)));
    const float radii_f = 3.f*sqrtf(fmaxf(lam, 1e-8f));

    const bool visible = (depth > 0.01f) &&
                         (mx > -256.f) && (mx < (float)IMG_W + 256.f) &&
                         (my > -256.f) && (my < (float)IMG_H + 256.f);
    radii_out[n] = visible ? radii_f : 0.f;

    const float det_c = fmaxf(det, 1e-10f);
    const float i00 =  d / det_c;
    const float i01 = -bb / det_c;
    const float i11 =  a / det_c;

    const float rad = fmaxf(radii_f, 1.f);
    float xlo = floorf(fminf(fmaxf(mx - rad,      0.f), (float)IMG_W));
    float xhi = floorf(fminf(fmaxf(mx + rad + 1.f, 0.f), (float)IMG_W));
    float ylo = floorf(fminf(fmaxf(my - rad,      0.f), (float)IMG_H));
    float yhi = floorf(fminf(fmaxf(my + rad + 1.f, 0.f), (float)IMG_H));
    if (!visible) { xlo = 1e9f; xhi = -1e9f; ylo = 1e9f; yhi = -1e9f; }

    // stable rank sort on key = visible ? depth : +inf (matches jnp.argsort)
    const float key = visible ? depth : INFINITY;
    skey[n] = key;
    __syncthreads();
    int rank = 0;
    for (int j = 0; j < N_G; ++j) {
        const float kj = skey[j];
        rank += (kj < key) || (kj == key && j < n);
    }

    float4* r = &recs[rank*4];
    r[0] = make_float4(xlo, xhi, ylo, yhi);
    r[1] = make_float4(mx, my, i00, i01);
    r[2] = make_float4(i11, opacity[n], depth, 0.f);
    r[3] = make_float4(cr, cg, cb, 0.f);
}

__global__ __launch_bounds__(256) void rasterize(
    const float4* __restrict__ recs, const float* __restrict__ bg,
    float* __restrict__ out)
{
    __shared__ float4 s_rec[N_G*4];   // 32 KB, compacted culled records
    __shared__ int   s_idx[N_G];
    __shared__ int   s_wcnt[4];

    const int tid = threadIdx.x;
    const int lane = tid & 63, w = tid >> 6;

    const float tx0 = (float)(blockIdx.x*16);         // tile pixel range [tx0, tx0+15]
    const float tx1 = tx0 + 16.f;
    const float ty0 = (float)(blockIdx.y*16);
    const float ty1 = ty0 + 16.f;

    // ---- per-tile culling: ordered stream compaction of gaussian indices ----
    int running = 0;
    #pragma unroll
    for (int c = 0; c < 2; ++c) {
        const int g = c*256 + tid;
        const float4 q0 = recs[g*4];                  // aligned dwordx4, stride 64 B
        // tile pixels x in [tx0, tx1): need xlo < tx1 and xhi > tx0 (pixel test is >=xlo, <xhi)
        const bool keep = (q0.x < tx1) && (q0.y > tx0) && (q0.z < ty1) && (q0.w > ty0);
        const unsigned long long m = __ballot(keep);
        const int pre = __popcll(m & ((1ull << lane) - 1ull));
        if (lane == 0) s_wcnt[w] = __popcll(m);
        __syncthreads();
        int off = running;
        for (int i = 0; i < w; ++i) off += s_wcnt[i];
        if (keep) s_idx[off + pre] = g;
        running += s_wcnt[0] + s_wcnt[1] + s_wcnt[2] + s_wcnt[3];
        __syncthreads();
    }
    const int cnt = running;

    // ---- gather culled records into contiguous LDS ----
    for (int i = tid; i < cnt*4; i += 256) {
        const int gi = s_idx[i >> 2];
        s_rec[i] = recs[gi*4 + (i & 3)];
    }
    __syncthreads();

    const float fpx = tx0 + (float)(tid & 15);
    const float fpy = ty0 + (float)(tid >> 4);

    float T = 1.f, cr = 0.f, cg = 0.f, cb = 0.f, D = 0.f;

    if (cnt > 0) {
        float4 a0 = s_rec[0], a1 = s_rec[1], a2 = s_rec[2], a3 = s_rec[3];
        for (int g = 0; g < cnt; ++g) {
            const int nx = (g + 1 < cnt) ? (g + 1) : g;   // prefetch next record
            const float4 b0 = s_rec[4*nx+0], b1 = s_rec[4*nx+1];
            const float4 b2 = s_rec[4*nx+2], b3 = s_rec[4*nx+3];
            if (fpx >= a0.x && fpx < a0.y && fpy >= a0.z && fpy < a0.w) {
                const float dx = fpx - a1.x, dy = fpy - a1.y;
                const float maha = a1.z*dx*dx + 2.f*a1.w*dx*dy + a2.x*dy*dy;
                const float alpha = fminf(a2.y*__expf(-0.5f*maha), 0.99f);
                const float wgt = T*alpha;
                cr += wgt*a3.x; cg += wgt*a3.y; cb += wgt*a3.z; D += wgt*a2.z;
                T *= (1.f - alpha);
            }
            a0 = b0; a1 = b1; a2 = b2; a3 = b3;
            if (__all(T < 1e-7f)) break;
        }
    }

    const int p = (int)fpy*IMG_W + (int)fpx;
    const float b0 = bg[0], b1 = bg[1], b2 = bg[2];
    out[p]                 = cr + b0*T;
    out[IMG_H*IMG_W   + p] = cg + b1*T;
    out[2*IMG_H*IMG_W + p] = cb + b2*T;
    out[3*IMG_H*IMG_W + p] = D;
    out[4*IMG_H*IMG_W + p] = 1.f - T;
}

extern "C" void kernel_launch(void* const* d_in, const int* in_sizes, int n_in,
                              void* d_out, int out_size, void* d_ws, size_t ws_size,
                              hipStream_t stream) {
    const float* xyz      = (const float*)d_in[0];
    const float* opacity  = (const float*)d_in[1];
    const float* features = (const float*)d_in[2];
    const float* cov      = (const float*)d_in[3];
    const float* Km       = (const float*)d_in[4];
    const float* w2c      = (const float*)d_in[5];
    const float* bg       = (const float*)d_in[6];
    float* out = (float*)d_out;
    float4* recs = (float4*)d_ws;                // 512*64 B = 32 KB
    float* radii_out = out + 5*IMG_H*IMG_W;      // render(3)+depth(1)+alpha(1) planes first

    preprocess_sort<<<1, N_G, 0, stream>>>(xyz, opacity, features, cov, Km, w2c,
                                           radii_out, recs);
    rasterize<<<dim3(IMG_W/16, IMG_H/16), 256, 0, stream>>>(recs, bg, out);
}

// Round 3
// 88.616 us; speedup vs baseline: 1.9115x; 1.0060x over previous
//
#include <hip/hip_runtime.h>
#include <math.h>

#define N_G   512
#define IMG_H 256
#define IMG_W 256

// record layout: 4 x float4 per gaussian (64 B), written in depth-rank order
//  q0 = (xlo, xhi, ylo, yhi)   -- sentinel (1e9,-1e9,1e9,-1e9) if invisible
//  q1 = (mx,  my,  i00, i01)
//  q2 = (i11, op,  dep, 0)
//  q3 = (r,   g,   b,   0)

__global__ __launch_bounds__(N_G) void preprocess_sort(
    const float* __restrict__ xyz, const float* __restrict__ opacity,
    const float* __restrict__ features, const float* __restrict__ cov,
    const float* __restrict__ Km, const float* __restrict__ w2c,
    float* __restrict__ radii_out, float4* __restrict__ recs)
{
    __shared__ float skey[N_G];
    const int n = threadIdx.x;

    const float R00=w2c[0], R01=w2c[1], R02=w2c[2],  t0=w2c[3];
    const float R10=w2c[4], R11=w2c[5], R12=w2c[6],  t1=w2c[7];
    const float R20=w2c[8], R21=w2c[9], R22=w2c[10], t2=w2c[11];
    const float K00=Km[0],K01=Km[1],K02=Km[2];
    const float K10=Km[3],K11=Km[4],K12=Km[5];
    const float K20=Km[6],K21=Km[7],K22=Km[8];

    const float wx = xyz[n*3+0], wy = xyz[n*3+1], wz = xyz[n*3+2];
    const float cx = R00*wx + R01*wy + R02*wz + t0;
    const float cy = R10*wx + R11*wy + R12*wz + t1;
    const float cz = R20*wx + R21*wy + R22*wz + t2;
    const float depth = cz;

    const float xh = K00*cx + K01*cy + K02*cz;
    const float yh = K10*cx + K11*cy + K12*cz;
    const float zh = K20*cx + K21*cy + K22*cz;
    const float zc = fmaxf(zh, 1e-8f);
    const float mx = xh / zc, my = yh / zc;

    // cam_pos = inv(w2c)[:3,3] (rigid inverse; exact for identity w2c)
    const float cpx = -(R00*t0 + R10*t1 + R20*t2);
    const float cpy = -(R01*t0 + R11*t1 + R21*t2);
    const float cpz = -(R02*t0 + R12*t1 + R22*t2);
    float vx = wx - cpx, vy = wy - cpy, vz = wz - cpz;
    const float nrm = fmaxf(sqrtf(vx*vx + vy*vy + vz*vz), 1e-12f);
    vx /= nrm; vy /= nrm; vz /= nrm;

    const float xx=vx*vx, yy=vy*vy, zz=vz*vz;
    const float sxy=vx*vy, syz=vy*vz, sxz=vx*vz;
    float sb[16];
    sb[0]  = 0.28209479177387814f;
    sb[1]  = -0.4886025119029199f*vy;
    sb[2]  =  0.4886025119029199f*vz;
    sb[3]  = -0.4886025119029199f*vx;
    sb[4]  =  1.0925484305920792f*sxy;
    sb[5]  = -1.0925484305920792f*syz;
    sb[6]  =  0.31539156525252005f*(2.f*zz - xx - yy);
    sb[7]  = -1.0925484305920792f*sxz;
    sb[8]  =  0.5462742152960396f*(xx - yy);
    sb[9]  = -0.5900435899266435f*vy*(3.f*xx - yy);
    sb[10] =  2.890611442640554f*sxy*vz;
    sb[11] = -0.4570457994644658f*vy*(4.f*zz - xx - yy);
    sb[12] =  0.3731763325901154f*vz*(2.f*zz - 3.f*xx - 3.f*yy);
    sb[13] = -0.4570457994644658f*vx*(4.f*zz - xx - yy);
    sb[14] =  1.445305721320277f*vz*(xx - yy);
    sb[15] = -0.5900435899266435f*vx*(xx - 3.f*yy);

    float cr = 0.f, cg = 0.f, cb = 0.f;
    const float* sh = &features[n*48];
    #pragma unroll
    for (int k = 0; k < 16; ++k) {
        cr += sb[k]*sh[k*3+0];
        cg += sb[k]*sh[k*3+1];
        cb += sb[k]*sh[k*3+2];
    }
    cr = fminf(fmaxf(cr + 0.5f, 0.f), 1.f);
    cg = fminf(fmaxf(cg + 0.5f, 0.f), 1.f);
    cb = fminf(fmaxf(cb + 0.5f, 0.f), 1.f);

    const float fx = K00, fy = K11;
    const float tz = fmaxf(cz, 1e-8f);
    const float tz2 = tz*tz;
    const float J00 = fx/tz,  J02 = -fx*cx/tz2;
    const float J11 = fy/tz,  J12 = -fy*cy/tz2;
    const float T00 = J00*R00 + J02*R20;
    const float T01 = J00*R01 + J02*R21;
    const float T02 = J00*R02 + J02*R22;
    const float T10 = J11*R10 + J12*R20;
    const float T11 = J11*R11 + J12*R21;
    const float T12 = J11*R12 + J12*R22;
    const float* S = &cov[n*9];
    const float u0 = S[0]*T00 + S[1]*T01 + S[2]*T02;
    const float u1 = S[3]*T00 + S[4]*T01 + S[5]*T02;
    const float u2 = S[6]*T00 + S[7]*T01 + S[8]*T02;
    const float a  = T00*u0 + T01*u1 + T02*u2 + 0.3f;
    const float bb = T10*u0 + T11*u1 + T12*u2;
    const float w0 = S[0]*T10 + S[1]*T11 + S[2]*T12;
    const float w1 = S[3]*T10 + S[4]*T11 + S[5]*T12;
    const float w2 = S[6]*T10 + S[7]*T11 + S[8]*T12;
    const float d  = T10*w0 + T11*w1 + T12*w2 + 0.3f;

    const float det   = a*d - bb*bb;
    const float trace = a + d;
    const float lam   = 0.5f*(trace + sqrtf(fmaxf(trace*trace - 4.f*det, 0.f)));
    const float radii_f = 3.f*sqrtf(fmaxf(lam, 1e-8f));

    const bool visible = (depth > 0.01f) &&
                         (mx > -256.f) && (mx < (float)IMG_W + 256.f) &&
                         (my > -256.f) && (my < (float)IMG_H + 256.f);
    radii_out[n] = visible ? radii_f : 0.f;

    const float det_c = fmaxf(det, 1e-10f);
    const float i00 =  d / det_c;
    const float i01 = -bb / det_c;
    const float i11 =  a / det_c;

    const float rad = fmaxf(radii_f, 1.f);
    float xlo = floorf(fminf(fmaxf(mx - rad,      0.f), (float)IMG_W));
    float xhi = floorf(fminf(fmaxf(mx + rad + 1.f, 0.f), (float)IMG_W));
    float ylo = floorf(fminf(fmaxf(my - rad,      0.f), (float)IMG_H));
    float yhi = floorf(fminf(fmaxf(my + rad + 1.f, 0.f), (float)IMG_H));
    if (!visible) { xlo = 1e9f; xhi = -1e9f; ylo = 1e9f; yhi = -1e9f; }

    // stable rank sort on key = visible ? depth : +inf (matches jnp.argsort)
    const float key = visible ? depth : INFINITY;
    skey[n] = key;
    __syncthreads();
    int rank = 0;
    for (int j = 0; j < N_G; ++j) {
        const float kj = skey[j];
        rank += (kj < key) || (kj == key && j < n);
    }

    float4* r = &recs[rank*4];
    r[0] = make_float4(xlo, xhi, ylo, yhi);
    r[1] = make_float4(mx, my, i00, i01);
    r[2] = make_float4(i11, opacity[n], depth, 0.f);
    r[3] = make_float4(cr, cg, cb, 0.f);
}

__global__ __launch_bounds__(256) void rasterize(
    const float4* __restrict__ recs, const float* __restrict__ bg,
    float* __restrict__ out)
{
    __shared__ float4 s_rec[N_G*4];   // 32 KB, all records (rank order)
    __shared__ float  s_xlo[N_G], s_xhi[N_G], s_ylo[N_G], s_yhi[N_G]; // SoA bbox, conflict-free
    __shared__ int    s_idx[N_G];     // culled indices, ascending = depth order
    __shared__ int    s_cnt[8];       // per-wave keep counts (chunk0: 0..3, chunk1: 4..7)

    const int tid  = threadIdx.x;
    const int lane = tid & 63, w = tid >> 6;

    // ---- coalesced stage of all 32 KB (contiguous float4 = conflict-free b128) ----
    #pragma unroll
    for (int i = 0; i < 8; ++i) {
        const int j = tid + i*256;
        const float4 v = recs[j];
        s_rec[j] = v;
        if ((j & 3) == 0) {            // q0 of gaussian j>>2 -> SoA bbox
            const int gi = j >> 2;
            s_xlo[gi] = v.x; s_xhi[gi] = v.y; s_ylo[gi] = v.z; s_yhi[gi] = v.w;
        }
    }
    __syncthreads();

    const float tx0 = (float)(blockIdx.x*16), tx1 = tx0 + 16.f;
    const float ty0 = (float)(blockIdx.y*16), ty1 = ty0 + 16.f;

    // ---- cull both 256-chunks in one pass (stride-4B SoA reads: no bank conflicts) ----
    const int g0 = tid, g1 = tid + 256;
    const bool k0 = (s_xlo[g0] < tx1) && (s_xhi[g0] > tx0) && (s_ylo[g0] < ty1) && (s_yhi[g0] > ty0);
    const bool k1 = (s_xlo[g1] < tx1) && (s_xhi[g1] > tx0) && (s_ylo[g1] < ty1) && (s_yhi[g1] > ty0);
    const unsigned long long m0 = __ballot(k0);
    const unsigned long long m1 = __ballot(k1);
    if (lane == 0) { s_cnt[w] = __popcll(m0); s_cnt[4+w] = __popcll(m1); }
    __syncthreads();
    const int c0 = s_cnt[0], c1 = s_cnt[1], c2 = s_cnt[2], c3 = s_cnt[3];
    const int c4 = s_cnt[4], c5 = s_cnt[5], c6 = s_cnt[6], c7 = s_cnt[7];
    const int total0 = c0 + c1 + c2 + c3;
    const int cnt    = total0 + c4 + c5 + c6 + c7;
    {
        const int base0 = (w>0?c0:0) + (w>1?c1:0) + (w>2?c2:0);
        const int base1 = total0 + (w>0?c4:0) + (w>1?c5:0) + (w>2?c6:0);
        const unsigned long long below = (1ull << lane) - 1ull;
        if (k0) s_idx[base0 + __popcll(m0 & below)] = g0;
        if (k1) s_idx[base1 + __popcll(m1 & below)] = g1;
    }
    __syncthreads();

    const float fpx = tx0 + (float)(tid & 15);
    const float fpy = ty0 + (float)(tid >> 4);

    float T = 1.f, cr = 0.f, cg = 0.f, cb = 0.f, D = 0.f;

    if (cnt > 0) {
        // idx prefetched one iter ahead; record reads are wave-uniform -> LDS broadcast
        int i_nxt = (cnt > 1) ? s_idx[1] : s_idx[0];
        int i_cur = s_idx[0];
        float4 a0 = s_rec[4*i_cur+0], a1 = s_rec[4*i_cur+1];
        float4 a2 = s_rec[4*i_cur+2], a3 = s_rec[4*i_cur+3];
        for (int g = 0; g < cnt; ++g) {
            const int gn2 = (g + 2 < cnt) ? (g + 2) : (cnt - 1);
            const int i_n2 = s_idx[gn2];                        // independent prefetch
            const float4 b0 = s_rec[4*i_nxt+0], b1 = s_rec[4*i_nxt+1];
            const float4 b2 = s_rec[4*i_nxt+2], b3 = s_rec[4*i_nxt+3];
            if (fpx >= a0.x && fpx < a0.y && fpy >= a0.z && fpy < a0.w) {
                const float dx = fpx - a1.x, dy = fpy - a1.y;
                const float maha = a1.z*dx*dx + 2.f*a1.w*dx*dy + a2.x*dy*dy;
                const float alpha = fminf(a2.y*__expf(-0.5f*maha), 0.99f);
                const float wgt = T*alpha;
                cr += wgt*a3.x; cg += wgt*a3.y; cb += wgt*a3.z; D += wgt*a2.z;
                T *= (1.f - alpha);
            }
            a0 = b0; a1 = b1; a2 = b2; a3 = b3;
            i_nxt = i_n2;
            if (__all(T < 1e-7f)) break;
        }
    }

    const int p = (int)fpy*IMG_W + (int)fpx;
    const float b0 = bg[0], b1 = bg[1], b2 = bg[2];
    out[p]                 = cr + b0*T;
    out[IMG_H*IMG_W   + p] = cg + b1*T;
    out[2*IMG_H*IMG_W + p] = cb + b2*T;
    out[3*IMG_H*IMG_W + p] = D;
    out[4*IMG_H*IMG_W + p] = 1.f - T;
}

extern "C" void kernel_launch(void* const* d_in, const int* in_sizes, int n_in,
                              void* d_out, int out_size, void* d_ws, size_t ws_size,
                              hipStream_t stream) {
    const float* xyz      = (const float*)d_in[0];
    const float* opacity  = (const float*)d_in[1];
    const float* features = (const float*)d_in[2];
    const float* cov      = (const float*)d_in[3];
    const float* Km       = (const float*)d_in[4];
    const float* w2c      = (const float*)d_in[5];
    const float* bg       = (const float*)d_in[6];
    float* out = (float*)d_out;
    float4* recs = (float4*)d_ws;                // 512*64 B = 32 KB
    float* radii_out = out + 5*IMG_H*IMG_W;      // render(3)+depth(1)+alpha(1) planes first

    preprocess_sort<<<1, N_G, 0, stream>>>(xyz, opacity, features, cov, Km, w2c,
                                           radii_out, recs);
    rasterize<<<dim3(IMG_W/16, IMG_H/16), 256, 0, stream>>>(recs, bg, out);
}

// Round 4
// 77.876 us; speedup vs baseline: 2.1751x; 1.1379x over previous
//
#include <hip/hip_runtime.h>
#include <math.h>

#define N_G   512
#define IMG_H 256
#define IMG_W 256

struct Rec {
    float mx, my, i00, i01, i11, op, dep, cr, cg, cb;
    float xlo, xhi, ylo, yhi, radii;
    bool  vis;
};

__device__ inline Rec make_rec(int n,
    const float* __restrict__ xyz, const float* __restrict__ opacity,
    const float* __restrict__ features, const float* __restrict__ cov,
    float R00,float R01,float R02,float t0,
    float R10,float R11,float R12,float t1,
    float R20,float R21,float R22,float t2,
    float K00,float K01,float K02,
    float K10,float K11,float K12,
    float K20,float K21,float K22)
{
    Rec o;
    const float wx = xyz[n*3+0], wy = xyz[n*3+1], wz = xyz[n*3+2];
    const float cx = R00*wx + R01*wy + R02*wz + t0;
    const float cy = R10*wx + R11*wy + R12*wz + t1;
    const float cz = R20*wx + R21*wy + R22*wz + t2;
    o.dep = cz;

    const float xh = K00*cx + K01*cy + K02*cz;
    const float yh = K10*cx + K11*cy + K12*cz;
    const float zh = K20*cx + K21*cy + K22*cz;
    const float zc = fmaxf(zh, 1e-8f);
    o.mx = xh / zc; o.my = yh / zc;

    // cam_pos = inv(w2c)[:3,3] (rigid inverse; exact for identity w2c)
    const float cpx = -(R00*t0 + R10*t1 + R20*t2);
    const float cpy = -(R01*t0 + R11*t1 + R21*t2);
    const float cpz = -(R02*t0 + R12*t1 + R22*t2);
    float vx = wx - cpx, vy = wy - cpy, vz = wz - cpz;
    const float nrm = fmaxf(sqrtf(vx*vx + vy*vy + vz*vz), 1e-12f);
    vx /= nrm; vy /= nrm; vz /= nrm;

    const float xx=vx*vx, yy=vy*vy, zz=vz*vz;
    const float sxy=vx*vy, syz=vy*vz, sxz=vx*vz;
    float sb[16];
    sb[0]  = 0.28209479177387814f;
    sb[1]  = -0.4886025119029199f*vy;
    sb[2]  =  0.4886025119029199f*vz;
    sb[3]  = -0.4886025119029199f*vx;
    sb[4]  =  1.0925484305920792f*sxy;
    sb[5]  = -1.0925484305920792f*syz;
    sb[6]  =  0.31539156525252005f*(2.f*zz - xx - yy);
    sb[7]  = -1.0925484305920792f*sxz;
    sb[8]  =  0.5462742152960396f*(xx - yy);
    sb[9]  = -0.5900435899266435f*vy*(3.f*xx - yy);
    sb[10] =  2.890611442640554f*sxy*vz;
    sb[11] = -0.4570457994644658f*vy*(4.f*zz - xx - yy);
    sb[12] =  0.3731763325901154f*vz*(2.f*zz - 3.f*xx - 3.f*yy);
    sb[13] = -0.4570457994644658f*vx*(4.f*zz - xx - yy);
    sb[14] =  1.445305721320277f*vz*(xx - yy);
    sb[15] = -0.5900435899266435f*vx*(xx - 3.f*yy);

    float cr = 0.f, cg = 0.f, cb = 0.f;
    const float* sh = &features[n*48];
    #pragma unroll
    for (int k = 0; k < 16; ++k) {
        cr += sb[k]*sh[k*3+0];
        cg += sb[k]*sh[k*3+1];
        cb += sb[k]*sh[k*3+2];
    }
    o.cr = fminf(fmaxf(cr + 0.5f, 0.f), 1.f);
    o.cg = fminf(fmaxf(cg + 0.5f, 0.f), 1.f);
    o.cb = fminf(fmaxf(cb + 0.5f, 0.f), 1.f);

    const float fx = K00, fy = K11;
    const float tz = fmaxf(cz, 1e-8f);
    const float tz2 = tz*tz;
    const float J00 = fx/tz,  J02 = -fx*cx/tz2;
    const float J11 = fy/tz,  J12 = -fy*cy/tz2;
    const float T00 = J00*R00 + J02*R20;
    const float T01 = J00*R01 + J02*R21;
    const float T02 = J00*R02 + J02*R22;
    const float T10 = J11*R10 + J12*R20;
    const float T11 = J11*R11 + J12*R21;
    const float T12 = J11*R12 + J12*R22;
    const float* S = &cov[n*9];
    const float u0 = S[0]*T00 + S[1]*T01 + S[2]*T02;
    const float u1 = S[3]*T00 + S[4]*T01 + S[5]*T02;
    const float u2 = S[6]*T00 + S[7]*T01 + S[8]*T02;
    const float a  = T00*u0 + T01*u1 + T02*u2 + 0.3f;
    const float bb = T10*u0 + T11*u1 + T12*u2;
    const float w0 = S[0]*T10 + S[1]*T11 + S[2]*T12;
    const float w1 = S[3]*T10 + S[4]*T11 + S[5]*T12;
    const float w2 = S[6]*T10 + S[7]*T11 + S[8]*T12;
    const float d  = T10*w0 + T11*w1 + T12*w2 + 0.3f;

    const float det   = a*d - bb*bb;
    const float trace = a + d;
    const float lam   = 0.5f*(trace + sqrtf(fmaxf(trace*trace - 4.f*det, 0.f)));
    const float radii_f = 3.f*sqrtf(fmaxf(lam, 1e-8f));

    o.vis = (o.dep > 0.01f) &&
            (o.mx > -256.f) && (o.mx < (float)IMG_W + 256.f) &&
            (o.my > -256.f) && (o.my < (float)IMG_H + 256.f);
    o.radii = o.vis ? radii_f : 0.f;

    const float det_c = fmaxf(det, 1e-10f);
    o.i00 =  d / det_c;
    o.i01 = -bb / det_c;
    o.i11 =  a / det_c;
    o.op  = opacity[n];

    const float rad = fmaxf(radii_f, 1.f);
    o.xlo = floorf(fminf(fmaxf(o.mx - rad,      0.f), (float)IMG_W));
    o.xhi = floorf(fminf(fmaxf(o.mx + rad + 1.f, 0.f), (float)IMG_W));
    o.ylo = floorf(fminf(fmaxf(o.my - rad,      0.f), (float)IMG_H));
    o.yhi = floorf(fminf(fmaxf(o.my + rad + 1.f, 0.f), (float)IMG_H));
    if (!o.vis) { o.xlo = 1e9f; o.xhi = -1e9f; o.ylo = 1e9f; o.yhi = -1e9f; }
    return o;
}

__global__ __launch_bounds__(256) void fused_render(
    const float* __restrict__ xyz, const float* __restrict__ opacity,
    const float* __restrict__ features, const float* __restrict__ cov,
    const float* __restrict__ Km, const float* __restrict__ w2c,
    const float* __restrict__ bg, float* __restrict__ out)
{
    // SoA records: stride-4B LDS writes (conflict-free), wave-uniform broadcast reads
    __shared__ float s_mx[N_G], s_my[N_G], s_i00[N_G], s_i01[N_G], s_i11[N_G];
    __shared__ float s_op[N_G], s_dep[N_G], s_cr[N_G], s_cg[N_G], s_cb[N_G];
    __shared__ float s_xlo[N_G], s_xhi[N_G], s_ylo[N_G], s_yhi[N_G];
    __shared__ float s_key[N_G];
    __shared__ int   s_idx[N_G], s_sorted[N_G];
    __shared__ int   s_cnt[8];

    const int tid  = threadIdx.x;
    const int lane = tid & 63, w = tid >> 6;

    const float R00=w2c[0], R01=w2c[1], R02=w2c[2],  t0=w2c[3];
    const float R10=w2c[4], R11=w2c[5], R12=w2c[6],  t1=w2c[7];
    const float R20=w2c[8], R21=w2c[9], R22=w2c[10], t2=w2c[11];
    const float K00=Km[0],K01=Km[1],K02=Km[2];
    const float K10=Km[3],K11=Km[4],K12=Km[5];
    const float K20=Km[6],K21=Km[7],K22=Km[8];

    // ---- redundant per-block preprocess: 2 gaussians/thread ----
    const bool writer = (blockIdx.x == 0) && (blockIdx.y == 0);
    float* radii_out = out + 5*IMG_H*IMG_W;
    #pragma unroll
    for (int c = 0; c < 2; ++c) {
        const int n = tid + c*256;
        const Rec r = make_rec(n, xyz, opacity, features, cov,
                               R00,R01,R02,t0, R10,R11,R12,t1, R20,R21,R22,t2,
                               K00,K01,K02, K10,K11,K12, K20,K21,K22);
        s_mx[n]=r.mx;  s_my[n]=r.my;  s_i00[n]=r.i00; s_i01[n]=r.i01; s_i11[n]=r.i11;
        s_op[n]=r.op;  s_dep[n]=r.dep; s_cr[n]=r.cr;  s_cg[n]=r.cg;  s_cb[n]=r.cb;
        s_xlo[n]=r.xlo; s_xhi[n]=r.xhi; s_ylo[n]=r.ylo; s_yhi[n]=r.yhi;
        if (writer) radii_out[n] = r.radii;
    }
    __syncthreads();

    const float tx0 = (float)(blockIdx.x*16), tx1 = tx0 + 16.f;
    const float ty0 = (float)(blockIdx.y*16), ty1 = ty0 + 16.f;

    // ---- tile cull -> compacted indices in ascending original order ----
    const int g0 = tid, g1 = tid + 256;
    const bool k0 = (s_xlo[g0] < tx1) && (s_xhi[g0] > tx0) && (s_ylo[g0] < ty1) && (s_yhi[g0] > ty0);
    const bool k1 = (s_xlo[g1] < tx1) && (s_xhi[g1] > tx0) && (s_ylo[g1] < ty1) && (s_yhi[g1] > ty0);
    const unsigned long long m0 = __ballot(k0);
    const unsigned long long m1 = __ballot(k1);
    if (lane == 0) { s_cnt[w] = __popcll(m0); s_cnt[4+w] = __popcll(m1); }
    __syncthreads();
    const int c0=s_cnt[0], c1=s_cnt[1], c2=s_cnt[2], c3=s_cnt[3];
    const int c4=s_cnt[4], c5=s_cnt[5], c6=s_cnt[6], c7=s_cnt[7];
    const int total0 = c0+c1+c2+c3;
    const int cnt    = total0+c4+c5+c6+c7;
    {
        const int base0 = (w>0?c0:0) + (w>1?c1:0) + (w>2?c2:0);
        const int base1 = total0 + (w>0?c4:0) + (w>1?c5:0) + (w>2?c6:0);
        const unsigned long long below = (1ull << lane) - 1ull;
        if (k0) s_idx[base0 + __popcll(m0 & below)] = g0;
        if (k1) s_idx[base1 + __popcll(m1 & below)] = g1;
    }
    __syncthreads();

    // ---- depth-rank sort of the culled subset (stable on (depth, orig idx)) ----
    // s_idx is ascending in original index, so position i is the stable tiebreak.
    for (int i = tid; i < cnt; i += 256) s_key[i] = s_dep[s_idx[i]];
    __syncthreads();
    for (int i = tid; i < cnt; i += 256) {
        const float ki = s_key[i];
        int rank = 0;
        for (int j = 0; j < cnt; ++j) {            // j wave-uniform -> LDS broadcast
            const float kj = s_key[j];
            rank += (kj < ki) || (kj == ki && j < i);
        }
        s_sorted[rank] = s_idx[i];
    }
    __syncthreads();

    // ---- composite front-to-back ----
    const float fpx = tx0 + (float)(tid & 15);
    const float fpy = ty0 + (float)(tid >> 4);

    float T = 1.f, acr = 0.f, acg = 0.f, acb = 0.f, D = 0.f;
    for (int g = 0; g < cnt; ++g) {
        const int i = s_sorted[g];                 // wave-uniform -> broadcast
        if (fpx >= s_xlo[i] && fpx < s_xhi[i] && fpy >= s_ylo[i] && fpy < s_yhi[i]) {
            const float dx = fpx - s_mx[i], dy = fpy - s_my[i];
            const float maha = s_i00[i]*dx*dx + 2.f*s_i01[i]*dx*dy + s_i11[i]*dy*dy;
            const float alpha = fminf(s_op[i]*__expf(-0.5f*maha), 0.99f);
            const float wgt = T*alpha;
            acr += wgt*s_cr[i]; acg += wgt*s_cg[i]; acb += wgt*s_cb[i]; D += wgt*s_dep[i];
            T *= (1.f - alpha);
        }
        if (__all(T < 1e-7f)) break;
    }

    const int p = (int)fpy*IMG_W + (int)fpx;
    const float b0 = bg[0], b1 = bg[1], b2 = bg[2];
    out[p]                 = acr + b0*T;
    out[IMG_H*IMG_W   + p] = acg + b1*T;
    out[2*IMG_H*IMG_W + p] = acb + b2*T;
    out[3*IMG_H*IMG_W + p] = D;
    out[4*IMG_H*IMG_W + p] = 1.f - T;
}

extern "C" void kernel_launch(void* const* d_in, const int* in_sizes, int n_in,
                              void* d_out, int out_size, void* d_ws, size_t ws_size,
                              hipStream_t stream) {
    const float* xyz      = (const float*)d_in[0];
    const float* opacity  = (const float*)d_in[1];
    const float* features = (const float*)d_in[2];
    const float* cov      = (const float*)d_in[3];
    const float* Km       = (const float*)d_in[4];
    const float* w2c      = (const float*)d_in[5];
    const float* bg       = (const float*)d_in[6];
    float* out = (float*)d_out;

    fused_render<<<dim3(IMG_W/16, IMG_H/16), 256, 0, stream>>>(
        xyz, opacity, features, cov, Km, w2c, bg, out);
}